// Round 1
// baseline (219.871 us; speedup 1.0000x reference)
//
#include <hip/hip_runtime.h>
#include <hip/hip_bf16.h>

// Problem constants
#define B_    32
#define T_    512
#define C_    384
#define D_    1536      // C*MULT
#define H_    1024
#define L_    255       // (T-SIZE)/STRIDE + 1
#define KP_   6144      // SIZE*D
#define ND_   16

using f32x4 = __attribute__((ext_vector_type(4))) float;
using s16x8 = __attribute__((ext_vector_type(8))) short;

__device__ __forceinline__ void gld_lds16(const void* g, void* l) {
    __builtin_amdgcn_global_load_lds(
        (const __attribute__((address_space(1))) void*)g,
        (__attribute__((address_space(3))) void*)l,
        16, 0, 0);
}

// ---------------- f32 -> bf16 conversion, 4 elems/thread ----------------
__global__ __launch_bounds__(256) void cvt_bf16(const float* __restrict__ in,
                                                __hip_bfloat16* __restrict__ out,
                                                int n4) {
    int i = blockIdx.x * 256 + threadIdx.x;
    if (i >= n4) return;
    float4 v = reinterpret_cast<const float4*>(in)[i];
    __hip_bfloat16 o[4] = {__float2bfloat16(v.x), __float2bfloat16(v.y),
                           __float2bfloat16(v.z), __float2bfloat16(v.w)};
    reinterpret_cast<ushort4*>(out)[i] = *reinterpret_cast<ushort4*>(o);
}

// ---------------- GEMM1: x1 = gelu(spikes @ Wg^T + bg) * 32, bf16 out ----
// A = spikes_bf16 [B][T][C], B = W_embed_bf16[date_idx] [D][C] (B^T layout)
// 128x128 tile, 4 waves (2x2 of 64x64), BK=32, double-buffered LDS.
__global__ __launch_bounds__(256) void gemm1_embed(
    const __hip_bfloat16* __restrict__ Sp,
    const __hip_bfloat16* __restrict__ We,
    const float* __restrict__ bEmb,
    const int* __restrict__ dateIdx,
    __hip_bfloat16* __restrict__ X1) {
    __shared__ __align__(16) char lds[2][16384];   // [buf][A 8KB | B 8KB]
    const int tid  = threadIdx.x;
    const int lane = tid & 63, wid = tid >> 6;
    const int wr = wid >> 1, wc = wid & 1;
    const int mt = blockIdx.x;      // 0..3
    const int nt = blockIdx.y;      // 0..11
    const int b  = blockIdx.z;      // 0..31
    const int m0 = mt * 128, n0 = nt * 128;
    const int didx = dateIdx[b];
    const __hip_bfloat16* A  = Sp + (size_t)b * T_ * C_;
    const __hip_bfloat16* Bm = We + (size_t)didx * D_ * C_;
    const int K = C_;          // 384
    const int KT = K / 32;     // 12

    auto stage = [&](int buf, int kt) {
        #pragma unroll
        for (int j = 0; j < 2; ++j) {
            int chunk = j * 256 + tid;          // 0..511
            int row = chunk >> 2;               // 0..127
            int kk  = (chunk & 3) * 8;          // 0,8,16,24
            gld_lds16(A + (size_t)(m0 + row) * K + kt * 32 + kk,
                      &lds[buf][j * 4096 + wid * 1024]);
            gld_lds16(Bm + (size_t)(n0 + row) * K + kt * 32 + kk,
                      &lds[buf][8192 + j * 4096 + wid * 1024]);
        }
    };

    f32x4 acc[4][4] = {};
    stage(0, 0);
    __syncthreads();
    int cur = 0;
    const int rl = lane & 15;
    const int kc = (lane >> 4) * 16;   // byte offset of lane's k-chunk
    for (int kt = 0; kt < KT; ++kt) {
        if (kt + 1 < KT) stage(cur ^ 1, kt + 1);
        const char* la = &lds[cur][0];
        const char* lb = &lds[cur][8192];
        s16x8 af[4], bf[4];
        #pragma unroll
        for (int mi = 0; mi < 4; ++mi)
            af[mi] = *(const s16x8*)(la + (wr * 64 + mi * 16 + rl) * 64 + kc);
        #pragma unroll
        for (int ni = 0; ni < 4; ++ni)
            bf[ni] = *(const s16x8*)(lb + (wc * 64 + ni * 16 + rl) * 64 + kc);
        #pragma unroll
        for (int mi = 0; mi < 4; ++mi)
            #pragma unroll
            for (int ni = 0; ni < 4; ++ni)
                acc[mi][ni] = __builtin_amdgcn_mfma_f32_16x16x32_bf16(
                    af[mi], bf[ni], acc[mi][ni], 0, 0, 0);
        __syncthreads();
        cur ^= 1;
    }

    // epilogue: + bias, exact gelu, * 32, store bf16
    #pragma unroll
    for (int mi = 0; mi < 4; ++mi) {
        #pragma unroll
        for (int ni = 0; ni < 4; ++ni) {
            int col = n0 + wc * 64 + ni * 16 + rl;              // d
            float bg = bEmb[didx * D_ + col];
            #pragma unroll
            for (int r = 0; r < 4; ++r) {
                int row = m0 + wr * 64 + mi * 16 + ((lane >> 4) * 4) + r;  // t
                float v = acc[mi][ni][r] + bg;
                float g = 0.5f * v * (1.0f + erff(v * 0.70710678118f)) * 32.0f;
                X1[((size_t)b * T_ + row) * D_ + col] = __float2bfloat16(g);
            }
        }
    }
}

// ---------------- GEMM2: out = patches @ W_proj^T + b_proj + pos_table[ts]
// patches row (b,l), k = s*D + d  ->  x1[b, 2l+s, d]
__global__ __launch_bounds__(256) void gemm2_proj(
    const __hip_bfloat16* __restrict__ X1,
    const __hip_bfloat16* __restrict__ Wp,     // [H][KP] bf16
    const float* __restrict__ bProj,
    const float* __restrict__ posTab,          // [MAXF][H]
    const int* __restrict__ tsIn,              // [B][T]
    float* __restrict__ outX) {                // [B][L][H]
    __shared__ __align__(16) char lds[2][16384];
    const int tid  = threadIdx.x;
    const int lane = tid & 63, wid = tid >> 6;
    const int wr = wid >> 1, wc = wid & 1;
    const int lt = blockIdx.x;      // 0..1
    const int nt = blockIdx.y;      // 0..7
    const int b  = blockIdx.z;      // 0..31
    const int l0 = lt * 128, n0 = nt * 128;
    const int KT = KP_ / 32;        // 192

    auto stage = [&](int buf, int kt) {
        int k0 = kt * 32;
        int s  = k0 / D_;           // constant within a 32-wide K-step
        int d0 = k0 % D_;
        #pragma unroll
        for (int j = 0; j < 2; ++j) {
            int chunk = j * 256 + tid;
            int row = chunk >> 2;
            int kk  = (chunk & 3) * 8;
            int l = l0 + row; if (l > L_ - 1) l = L_ - 1;   // clamp tail row
            int t = 2 * l + s;                               // <= 511
            gld_lds16(X1 + ((size_t)b * T_ + t) * D_ + d0 + kk,
                      &lds[buf][j * 4096 + wid * 1024]);
            gld_lds16(Wp + (size_t)(n0 + row) * KP_ + k0 + kk,
                      &lds[buf][8192 + j * 4096 + wid * 1024]);
        }
    };

    f32x4 acc[4][4] = {};
    stage(0, 0);
    __syncthreads();
    int cur = 0;
    const int rl = lane & 15;
    const int kc = (lane >> 4) * 16;
    for (int kt = 0; kt < KT; ++kt) {
        if (kt + 1 < KT) stage(cur ^ 1, kt + 1);
        const char* la = &lds[cur][0];
        const char* lb = &lds[cur][8192];
        s16x8 af[4], bf[4];
        #pragma unroll
        for (int mi = 0; mi < 4; ++mi)
            af[mi] = *(const s16x8*)(la + (wr * 64 + mi * 16 + rl) * 64 + kc);
        #pragma unroll
        for (int ni = 0; ni < 4; ++ni)
            bf[ni] = *(const s16x8*)(lb + (wc * 64 + ni * 16 + rl) * 64 + kc);
        #pragma unroll
        for (int mi = 0; mi < 4; ++mi)
            #pragma unroll
            for (int ni = 0; ni < 4; ++ni)
                acc[mi][ni] = __builtin_amdgcn_mfma_f32_16x16x32_bf16(
                    af[mi], bf[ni], acc[mi][ni], 0, 0, 0);
        __syncthreads();
        cur ^= 1;
    }

    #pragma unroll
    for (int mi = 0; mi < 4; ++mi) {
        #pragma unroll
        for (int ni = 0; ni < 4; ++ni) {
            int h = n0 + wc * 64 + ni * 16 + rl;
            float bp = bProj[h];
            #pragma unroll
            for (int r = 0; r < 4; ++r) {
                int l = l0 + wr * 64 + mi * 16 + ((lane >> 4) * 4) + r;
                if (l < L_) {
                    int tsv = tsIn[b * T_ + l];
                    float v = acc[mi][ni][r] + bp + posTab[(size_t)tsv * H_ + h];
                    outX[((size_t)b * L_ + l) * H_ + h] = v;
                }
            }
        }
    }
}

// ---------------- mask & ts side outputs (written as float values) -------
__global__ __launch_bounds__(256) void mask_ts(const int* __restrict__ mIn,
                                               const int* __restrict__ tIn,
                                               float* __restrict__ out) {
    int i = blockIdx.x * 256 + threadIdx.x;
    if (i >= B_ * L_) return;
    int b = i / L_, l = i % L_;
    const int* mb = mIn + b * T_ + 2 * l;
    int m = mb[0] * mb[1] * mb[2] * mb[3];
    const size_t offM = (size_t)B_ * L_ * H_;
    out[offM + i] = (float)m;
    out[offM + (size_t)B_ * L_ + i] = (float)tIn[b * T_ + l];
}

extern "C" void kernel_launch(void* const* d_in, const int* in_sizes, int n_in,
                              void* d_out, int out_size, void* d_ws, size_t ws_size,
                              hipStream_t stream) {
    (void)in_sizes; (void)n_in; (void)out_size; (void)ws_size;
    const float* spikes  = (const float*)d_in[0];
    const int*   smask   = (const int*)d_in[1];
    const int*   sts     = (const int*)d_in[2];
    const int*   dateIdx = (const int*)d_in[3];
    const float* Wemb    = (const float*)d_in[4];
    const float* bEmb    = (const float*)d_in[5];
    const float* Wproj   = (const float*)d_in[6];
    const float* bProj   = (const float*)d_in[7];
    const float* posTab  = (const float*)d_in[8];
    float* out = (float*)d_out;

    // workspace layout (bytes):
    // X1 bf16   [B][T][D]  : 32*512*1536*2 = 50331648
    // SpB bf16  [B][T][C]  : 12582912
    // WeB bf16  [ND][D][C] : 18874368
    // WpB bf16  [H][KP]    : 12582912
    char* ws = (char*)d_ws;
    __hip_bfloat16* X1  = (__hip_bfloat16*)(ws);
    __hip_bfloat16* SpB = (__hip_bfloat16*)(ws + 50331648);
    __hip_bfloat16* WeB = (__hip_bfloat16*)(ws + 50331648 + 12582912);
    __hip_bfloat16* WpB = (__hip_bfloat16*)(ws + 50331648 + 12582912 + 18874368);

    // conversions (element counts / 4)
    cvt_bf16<<<6144, 256, 0, stream>>>(spikes, SpB, 1572864);   // 32*512*384
    cvt_bf16<<<9216, 256, 0, stream>>>(Wemb,  WeB, 2359296);    // 16*1536*384
    cvt_bf16<<<6144, 256, 0, stream>>>(Wproj, WpB, 1572864);    // 1024*6144

    dim3 g1(4, 12, 32);
    gemm1_embed<<<g1, 256, 0, stream>>>(SpB, WeB, bEmb, dateIdx, X1);

    dim3 g2(2, 8, 32);
    gemm2_proj<<<g2, 256, 0, stream>>>(X1, WpB, bProj, posTab, sts, out);

    mask_ts<<<32, 256, 0, stream>>>(smask, sts, out);
}

// Round 2
// 206.124 us; speedup vs baseline: 1.0667x; 1.0667x over previous
//
#include <hip/hip_runtime.h>
#include <hip/hip_bf16.h>

// Problem constants
#define B_    32
#define T_    512
#define C_    384
#define D_    1536      // C*MULT
#define H_    1024
#define L_    255       // (T-SIZE)/STRIDE + 1
#define KP_   6144      // SIZE*D
#define ND_   16

using f32x4 = __attribute__((ext_vector_type(4))) float;
using s16x8 = __attribute__((ext_vector_type(8))) short;

__device__ __forceinline__ void gld_lds16(const void* g, void* l) {
    __builtin_amdgcn_global_load_lds(
        (const __attribute__((address_space(1))) void*)g,
        (__attribute__((address_space(3))) void*)l,
        16, 0, 0);
}

// ---------------- f32 -> bf16 conversion, 4 elems/thread ----------------
__global__ __launch_bounds__(256) void cvt_bf16(const float* __restrict__ in,
                                                __hip_bfloat16* __restrict__ out,
                                                int n4) {
    int i = blockIdx.x * 256 + threadIdx.x;
    if (i >= n4) return;
    float4 v = reinterpret_cast<const float4*>(in)[i];
    __hip_bfloat16 o[4] = {__float2bfloat16(v.x), __float2bfloat16(v.y),
                           __float2bfloat16(v.z), __float2bfloat16(v.w)};
    reinterpret_cast<ushort4*>(out)[i] = *reinterpret_cast<ushort4*>(o);
}

// LDS tile geometry (both GEMMs): 128 rows x 64 bf16 (128 B = 8 chunks of 16B)
// XOR swizzle: physical chunk-in-row = logical_chunk ^ (row & 7).
// Applied on (a) pre-swizzled global SOURCE during global_load_lds staging
// (LDS dest linear, per m104/m173) and (b) the ds_read_b128 address.
// Per 16-lane quarter-wave this spreads 16 rows x 16B across all 32 banks.

// ---------------- GEMM1: x1 = gelu(spikes @ Wg^T + bg) * 32, bf16 out ----
__global__ __launch_bounds__(256) void gemm1_embed(
    const __hip_bfloat16* __restrict__ Sp,
    const __hip_bfloat16* __restrict__ We,
    const float* __restrict__ bEmb,
    const int* __restrict__ dateIdx,
    __hip_bfloat16* __restrict__ X1) {
    __shared__ __align__(16) char lds[2][32768];   // [buf][A 16KB | B 16KB]
    const int tid  = threadIdx.x;
    const int lane = tid & 63, wid = tid >> 6;
    const int wr = wid >> 1, wc = wid & 1;
    const int m0 = blockIdx.x * 128;     // t
    const int n0 = blockIdx.y * 128;     // d
    const int b  = blockIdx.z;
    const int didx = dateIdx[b];
    const __hip_bfloat16* A  = Sp + (size_t)b * T_ * C_;
    const __hip_bfloat16* Bm = We + (size_t)didx * D_ * C_;
    const int KT = C_ / 64;              // 6

    auto stage = [&](int buf, int kt) {
        int k0 = kt * 64;
        #pragma unroll
        for (int j = 0; j < 4; ++j) {
            int p    = wid * 256 + j * 64 + lane;    // physical 16B chunk id
            int row  = p >> 3;
            int clog = (p & 7) ^ (row & 7);          // inverse-swizzled source
            gld_lds16(A + (size_t)(m0 + row) * C_ + k0 + clog * 8,
                      &lds[buf][(wid * 256 + j * 64) * 16]);
            gld_lds16(Bm + (size_t)(n0 + row) * C_ + k0 + clog * 8,
                      &lds[buf][16384 + (wid * 256 + j * 64) * 16]);
        }
    };

    f32x4 acc[4][4] = {};
    stage(0, 0);
    __syncthreads();
    int cur = 0;
    const int rl = lane & 15;
    const int g  = lane >> 4;
    const int rA = wr * 64 + rl, rB = wc * 64 + rl;
    const int sxA = rA & 7, sxB = rB & 7;
    for (int kt = 0; kt < KT; ++kt) {
        if (kt + 1 < KT) stage(cur ^ 1, kt + 1);
        const char* la = &lds[cur][0];
        const char* lb = &lds[cur][16384];
        #pragma unroll
        for (int ks = 0; ks < 2; ++ks) {
            s16x8 af[4], bf[4];
            #pragma unroll
            for (int mi = 0; mi < 4; ++mi)
                af[mi] = *(const s16x8*)(la + rA * 128 + mi * 2048 +
                                         (((ks * 4 + g) ^ sxA) << 4));
            #pragma unroll
            for (int ni = 0; ni < 4; ++ni)
                bf[ni] = *(const s16x8*)(lb + rB * 128 + ni * 2048 +
                                         (((ks * 4 + g) ^ sxB) << 4));
            #pragma unroll
            for (int mi = 0; mi < 4; ++mi)
                #pragma unroll
                for (int ni = 0; ni < 4; ++ni)
                    acc[mi][ni] = __builtin_amdgcn_mfma_f32_16x16x32_bf16(
                        af[mi], bf[ni], acc[mi][ni], 0, 0, 0);
        }
        __syncthreads();
        cur ^= 1;
    }

    #pragma unroll
    for (int mi = 0; mi < 4; ++mi) {
        #pragma unroll
        for (int ni = 0; ni < 4; ++ni) {
            int col = n0 + wc * 64 + ni * 16 + rl;              // d
            float bg = bEmb[didx * D_ + col];
            #pragma unroll
            for (int r = 0; r < 4; ++r) {
                int row = m0 + wr * 64 + mi * 16 + g * 4 + r;   // t
                float v = acc[mi][ni][r] + bg;
                float gl = 0.5f * v * (1.0f + erff(v * 0.70710678118f)) * 32.0f;
                X1[((size_t)b * T_ + row) * D_ + col] = __float2bfloat16(gl);
            }
        }
    }
}

// ---------------- GEMM2: out = patches @ W_proj^T + b_proj + pos_table[ts]
__global__ __launch_bounds__(256) void gemm2_proj(
    const __hip_bfloat16* __restrict__ X1,
    const __hip_bfloat16* __restrict__ Wp,     // [H][KP] bf16
    const float* __restrict__ bProj,
    const float* __restrict__ posTab,          // [MAXF][H]
    const int* __restrict__ tsIn,              // [B][T]
    float* __restrict__ outX) {                // [B][L][H]
    __shared__ __align__(16) char lds[2][32768];
    const int tid  = threadIdx.x;
    const int lane = tid & 63, wid = tid >> 6;
    const int wr = wid >> 1, wc = wid & 1;
    const int l0 = blockIdx.x * 128;
    const int n0 = blockIdx.y * 128;
    const int b  = blockIdx.z;
    const int KT = KP_ / 64;                   // 96

    auto stage = [&](int buf, int kt) {
        int k0 = kt * 64;
        int s  = k0 / D_;                      // constant within 64-wide step
        int d0 = k0 % D_;
        #pragma unroll
        for (int j = 0; j < 4; ++j) {
            int p    = wid * 256 + j * 64 + lane;
            int row  = p >> 3;
            int clog = (p & 7) ^ (row & 7);
            int l = l0 + row; if (l > L_ - 1) l = L_ - 1;
            int t = 2 * l + s;
            gld_lds16(X1 + ((size_t)b * T_ + t) * D_ + d0 + clog * 8,
                      &lds[buf][(wid * 256 + j * 64) * 16]);
            gld_lds16(Wp + (size_t)(n0 + row) * KP_ + k0 + clog * 8,
                      &lds[buf][16384 + (wid * 256 + j * 64) * 16]);
        }
    };

    f32x4 acc[4][4] = {};
    stage(0, 0);
    __syncthreads();
    int cur = 0;
    const int rl = lane & 15;
    const int g  = lane >> 4;
    const int rA = wr * 64 + rl, rB = wc * 64 + rl;
    const int sxA = rA & 7, sxB = rB & 7;
    for (int kt = 0; kt < KT; ++kt) {
        if (kt + 1 < KT) stage(cur ^ 1, kt + 1);
        const char* la = &lds[cur][0];
        const char* lb = &lds[cur][16384];
        #pragma unroll
        for (int ks = 0; ks < 2; ++ks) {
            s16x8 af[4], bf[4];
            #pragma unroll
            for (int mi = 0; mi < 4; ++mi)
                af[mi] = *(const s16x8*)(la + rA * 128 + mi * 2048 +
                                         (((ks * 4 + g) ^ sxA) << 4));
            #pragma unroll
            for (int ni = 0; ni < 4; ++ni)
                bf[ni] = *(const s16x8*)(lb + rB * 128 + ni * 2048 +
                                         (((ks * 4 + g) ^ sxB) << 4));
            #pragma unroll
            for (int mi = 0; mi < 4; ++mi)
                #pragma unroll
                for (int ni = 0; ni < 4; ++ni)
                    acc[mi][ni] = __builtin_amdgcn_mfma_f32_16x16x32_bf16(
                        af[mi], bf[ni], acc[mi][ni], 0, 0, 0);
        }
        __syncthreads();
        cur ^= 1;
    }

    #pragma unroll
    for (int mi = 0; mi < 4; ++mi) {
        #pragma unroll
        for (int ni = 0; ni < 4; ++ni) {
            int h = n0 + wc * 64 + ni * 16 + rl;
            float bp = bProj[h];
            #pragma unroll
            for (int r = 0; r < 4; ++r) {
                int l = l0 + wr * 64 + mi * 16 + g * 4 + r;
                if (l < L_) {
                    int tsv = tsIn[b * T_ + l];
                    float v = acc[mi][ni][r] + bp + posTab[(size_t)tsv * H_ + h];
                    outX[((size_t)b * L_ + l) * H_ + h] = v;
                }
            }
        }
    }
}

// ---------------- mask & ts side outputs (written as float values) -------
__global__ __launch_bounds__(256) void mask_ts(const int* __restrict__ mIn,
                                               const int* __restrict__ tIn,
                                               float* __restrict__ out) {
    int i = blockIdx.x * 256 + threadIdx.x;
    if (i >= B_ * L_) return;
    int b = i / L_, l = i % L_;
    const int* mb = mIn + b * T_ + 2 * l;
    int m = mb[0] * mb[1] * mb[2] * mb[3];
    const size_t offM = (size_t)B_ * L_ * H_;
    out[offM + i] = (float)m;
    out[offM + (size_t)B_ * L_ + i] = (float)tIn[b * T_ + l];
}

extern "C" void kernel_launch(void* const* d_in, const int* in_sizes, int n_in,
                              void* d_out, int out_size, void* d_ws, size_t ws_size,
                              hipStream_t stream) {
    (void)in_sizes; (void)n_in; (void)out_size; (void)ws_size;
    const float* spikes  = (const float*)d_in[0];
    const int*   smask   = (const int*)d_in[1];
    const int*   sts     = (const int*)d_in[2];
    const int*   dateIdx = (const int*)d_in[3];
    const float* Wemb    = (const float*)d_in[4];
    const float* bEmb    = (const float*)d_in[5];
    const float* Wproj   = (const float*)d_in[6];
    const float* bProj   = (const float*)d_in[7];
    const float* posTab  = (const float*)d_in[8];
    float* out = (float*)d_out;

    // workspace layout (bytes):
    // X1 bf16   [B][T][D]  : 50331648
    // SpB bf16  [B][T][C]  : 12582912
    // WeB bf16  [ND][D][C] : 18874368
    // WpB bf16  [H][KP]    : 12582912
    char* ws = (char*)d_ws;
    __hip_bfloat16* X1  = (__hip_bfloat16*)(ws);
    __hip_bfloat16* SpB = (__hip_bfloat16*)(ws + 50331648);
    __hip_bfloat16* WeB = (__hip_bfloat16*)(ws + 50331648 + 12582912);
    __hip_bfloat16* WpB = (__hip_bfloat16*)(ws + 50331648 + 12582912 + 18874368);

    cvt_bf16<<<6144, 256, 0, stream>>>(spikes, SpB, 1572864);   // 32*512*384
    cvt_bf16<<<9216, 256, 0, stream>>>(Wemb,  WeB, 2359296);    // 16*1536*384
    cvt_bf16<<<6144, 256, 0, stream>>>(Wproj, WpB, 1572864);    // 1024*6144

    dim3 g1(4, 12, 32);
    gemm1_embed<<<g1, 256, 0, stream>>>(SpB, WeB, bEmb, dateIdx, X1);

    dim3 g2(2, 8, 32);
    gemm2_proj<<<g2, 256, 0, stream>>>(X1, WpB, bProj, posTab, sts, out);

    mask_ts<<<32, 256, 0, stream>>>(smask, sts, out);
}

// Round 3
// 204.792 us; speedup vs baseline: 1.0736x; 1.0065x over previous
//
#include <hip/hip_runtime.h>
#include <hip/hip_bf16.h>

// Problem constants
#define B_    32
#define T_    512
#define C_    384
#define D_    1536      // C*MULT
#define H_    1024
#define L_    255       // (T-SIZE)/STRIDE + 1
#define KP_   6144      // SIZE*D
#define ND_   16

// GEMM template geometry: BM=256, BN=128, BK=64, 512 threads = 8 waves (4Mx2N),
// per-wave 64x64 output. Triple-buffered LDS (3 x 48KB = 144KB dynamic),
// counted vmcnt(12) pipeline: tile kt's loads issued at iter kt-2.
#define BUFB 49152      // bytes per LDS buffer (A 32KB + B 16KB)

using f32x4 = __attribute__((ext_vector_type(4))) float;
using s16x8 = __attribute__((ext_vector_type(8))) short;

__device__ __forceinline__ void gld_lds16(const void* g, void* l) {
    __builtin_amdgcn_global_load_lds(
        (const __attribute__((address_space(1))) void*)g,
        (__attribute__((address_space(3))) void*)l,
        16, 0, 0);
}

// ---------------- f32 -> bf16 conversion, 4 elems/thread ----------------
__global__ __launch_bounds__(256) void cvt_bf16(const float* __restrict__ in,
                                                __hip_bfloat16* __restrict__ out,
                                                int n4) {
    int i = blockIdx.x * 256 + threadIdx.x;
    if (i >= n4) return;
    float4 v = reinterpret_cast<const float4*>(in)[i];
    __hip_bfloat16 o[4] = {__float2bfloat16(v.x), __float2bfloat16(v.y),
                           __float2bfloat16(v.z), __float2bfloat16(v.w)};
    reinterpret_cast<ushort4*>(out)[i] = *reinterpret_cast<ushort4*>(o);
}

// Compute one K-tile (BK=64, two ks-phases of 32) for this wave's 64x64 tile.
// la: A buffer [256 rows][64 bf16] XOR-swizzled; lb: B buffer [128][64].
__device__ __forceinline__ void tile_compute(const char* la, const char* lb,
                                             f32x4 (&acc)[4][4],
                                             int rA, int rB, int g) {
    const int sxA = rA & 7, sxB = rB & 7;
    s16x8 af0[4], bf0[4], af1[4], bf1[4];
    #pragma unroll
    for (int mi = 0; mi < 4; ++mi)
        af0[mi] = *(const s16x8*)(la + rA * 128 + mi * 2048 + ((g ^ sxA) << 4));
    #pragma unroll
    for (int ni = 0; ni < 4; ++ni)
        bf0[ni] = *(const s16x8*)(lb + rB * 128 + ni * 2048 + ((g ^ sxB) << 4));
    #pragma unroll
    for (int mi = 0; mi < 4; ++mi)
        af1[mi] = *(const s16x8*)(la + rA * 128 + mi * 2048 + (((4 + g) ^ sxA) << 4));
    #pragma unroll
    for (int ni = 0; ni < 4; ++ni)
        bf1[ni] = *(const s16x8*)(lb + rB * 128 + ni * 2048 + (((4 + g) ^ sxB) << 4));
    asm volatile("s_waitcnt lgkmcnt(8)" ::: "memory");
    __builtin_amdgcn_sched_barrier(0);
    __builtin_amdgcn_s_setprio(1);
    #pragma unroll
    for (int mi = 0; mi < 4; ++mi)
        #pragma unroll
        for (int ni = 0; ni < 4; ++ni)
            acc[mi][ni] = __builtin_amdgcn_mfma_f32_16x16x32_bf16(
                af0[mi], bf0[ni], acc[mi][ni], 0, 0, 0);
    __builtin_amdgcn_s_setprio(0);
    asm volatile("s_waitcnt lgkmcnt(0)" ::: "memory");
    __builtin_amdgcn_sched_barrier(0);
    __builtin_amdgcn_s_setprio(1);
    #pragma unroll
    for (int mi = 0; mi < 4; ++mi)
        #pragma unroll
        for (int ni = 0; ni < 4; ++ni)
            acc[mi][ni] = __builtin_amdgcn_mfma_f32_16x16x32_bf16(
                af1[mi], bf1[ni], acc[mi][ni], 0, 0, 0);
    __builtin_amdgcn_s_setprio(0);
}

// ---------------- GEMM1: x1 = gelu(spikes @ Wg^T + bg) * 32, bf16 out ----
// grid (2 Mtiles, 12 Ntiles, 32 b), 512 threads.
__global__ __launch_bounds__(512, 2) void gemm1_embed(
    const __hip_bfloat16* __restrict__ Sp,
    const __hip_bfloat16* __restrict__ We,
    const float* __restrict__ bEmb,
    const int* __restrict__ dateIdx,
    __hip_bfloat16* __restrict__ X1) {
    extern __shared__ __align__(16) char lds[];
    const int tid  = threadIdx.x;
    const int lane = tid & 63, wid = tid >> 6;
    const int wr = wid >> 1, wc = wid & 1;
    const int m0 = blockIdx.x * 256;
    const int n0 = blockIdx.y * 128;
    const int b  = blockIdx.z;
    const int didx = dateIdx[b];
    const __hip_bfloat16* A  = Sp + (size_t)b * T_ * C_;
    const __hip_bfloat16* Bm = We + (size_t)didx * D_ * C_;
    const int KT = C_ / 64;              // 6

    auto stage = [&](int kt, int buf) {
        char* lA = lds + buf * BUFB;
        char* lB = lA + 32768;
        int k0 = kt * 64;
        #pragma unroll
        for (int i = 0; i < 4; ++i) {
            int p = i * 512 + tid;
            int row = p >> 3;
            int clog = (p & 7) ^ (row & 7);
            gld_lds16(A + (size_t)(m0 + row) * C_ + k0 + clog * 8,
                      lA + (i * 512 + wid * 64) * 16);
        }
        #pragma unroll
        for (int i = 0; i < 2; ++i) {
            int p = i * 512 + tid;
            int row = p >> 3;
            int clog = (p & 7) ^ (row & 7);
            gld_lds16(Bm + (size_t)(n0 + row) * C_ + k0 + clog * 8,
                      lB + (i * 512 + wid * 64) * 16);
        }
    };

    f32x4 acc[4][4] = {};
    const int rl = lane & 15, g = lane >> 4;
    const int rA = wr * 64 + rl, rB = wc * 64 + rl;

    stage(0, 0);
    stage(1, 1);
    for (int kt = 0; kt < KT - 2; ++kt) {
        stage(kt + 2, (kt + 2) % 3);
        asm volatile("s_waitcnt vmcnt(12)" ::: "memory");
        __builtin_amdgcn_s_barrier();
        const char* la = lds + (kt % 3) * BUFB;
        tile_compute(la, la + 32768, acc, rA, rB, g);
        __builtin_amdgcn_s_barrier();
    }
    asm volatile("s_waitcnt vmcnt(6)" ::: "memory");
    __builtin_amdgcn_s_barrier();
    {
        const char* la = lds + ((KT - 2) % 3) * BUFB;
        tile_compute(la, la + 32768, acc, rA, rB, g);
    }
    asm volatile("s_waitcnt vmcnt(0)" ::: "memory");
    __builtin_amdgcn_s_barrier();
    {
        const char* la = lds + ((KT - 1) % 3) * BUFB;
        tile_compute(la, la + 32768, acc, rA, rB, g);
    }

    // epilogue: + bias, exact gelu, * 32, store bf16
    #pragma unroll
    for (int mi = 0; mi < 4; ++mi) {
        #pragma unroll
        for (int ni = 0; ni < 4; ++ni) {
            int col = n0 + wc * 64 + ni * 16 + rl;              // d
            float bg = bEmb[didx * D_ + col];
            #pragma unroll
            for (int r = 0; r < 4; ++r) {
                int row = m0 + wr * 64 + mi * 16 + g * 4 + r;   // t
                float v = acc[mi][ni][r] + bg;
                float gl = 0.5f * v * (1.0f + erff(v * 0.70710678118f)) * 32.0f;
                X1[((size_t)b * T_ + row) * D_ + col] = __float2bfloat16(gl);
            }
        }
    }
}

// ---------------- GEMM2: out = patches @ W_proj^T + b_proj + pos_table[ts]
// grid (1, 8 Ntiles, 32 b), 512 threads. Rows = l (0..254, row 255 clamped).
__global__ __launch_bounds__(512, 2) void gemm2_proj(
    const __hip_bfloat16* __restrict__ X1,
    const __hip_bfloat16* __restrict__ Wp,     // [H][KP] bf16
    const float* __restrict__ bProj,
    const float* __restrict__ posTab,          // [MAXF][H]
    const int* __restrict__ tsIn,              // [B][T]
    float* __restrict__ outX) {                // [B][L][H]
    extern __shared__ __align__(16) char lds[];
    const int tid  = threadIdx.x;
    const int lane = tid & 63, wid = tid >> 6;
    const int wr = wid >> 1, wc = wid & 1;
    const int n0 = blockIdx.y * 128;
    const int b  = blockIdx.z;
    const __hip_bfloat16* Xb = X1 + (size_t)b * T_ * D_;
    const int KT = KP_ / 64;                   // 96

    auto stage = [&](int kt, int buf) {
        char* lA = lds + buf * BUFB;
        char* lB = lA + 32768;
        int s  = kt / 24;                      // 0..3
        int d0 = (kt % 24) * 64;
        #pragma unroll
        for (int i = 0; i < 4; ++i) {
            int p = i * 512 + tid;
            int row = p >> 3;
            int clog = (p & 7) ^ (row & 7);
            int l = row < 255 ? row : 254;
            gld_lds16(Xb + (size_t)(2 * l + s) * D_ + d0 + clog * 8,
                      lA + (i * 512 + wid * 64) * 16);
        }
        #pragma unroll
        for (int i = 0; i < 2; ++i) {
            int p = i * 512 + tid;
            int row = p >> 3;
            int clog = (p & 7) ^ (row & 7);
            gld_lds16(Wp + (size_t)(n0 + row) * KP_ + kt * 64 + clog * 8,
                      lB + (i * 512 + wid * 64) * 16);
        }
    };

    f32x4 acc[4][4] = {};
    const int rl = lane & 15, g = lane >> 4;
    const int rA = wr * 64 + rl, rB = wc * 64 + rl;

    stage(0, 0);
    stage(1, 1);
    for (int kt = 0; kt < KT - 2; ++kt) {
        stage(kt + 2, (kt + 2) % 3);
        asm volatile("s_waitcnt vmcnt(12)" ::: "memory");
        __builtin_amdgcn_s_barrier();
        const char* la = lds + (kt % 3) * BUFB;
        tile_compute(la, la + 32768, acc, rA, rB, g);
        __builtin_amdgcn_s_barrier();
    }
    asm volatile("s_waitcnt vmcnt(6)" ::: "memory");
    __builtin_amdgcn_s_barrier();
    {
        const char* la = lds + ((KT - 2) % 3) * BUFB;
        tile_compute(la, la + 32768, acc, rA, rB, g);
    }
    asm volatile("s_waitcnt vmcnt(0)" ::: "memory");
    __builtin_amdgcn_s_barrier();
    {
        const char* la = lds + ((KT - 1) % 3) * BUFB;
        tile_compute(la, la + 32768, acc, rA, rB, g);
    }

    #pragma unroll
    for (int mi = 0; mi < 4; ++mi) {
        #pragma unroll
        for (int ni = 0; ni < 4; ++ni) {
            int h = n0 + wc * 64 + ni * 16 + rl;
            float bp = bProj[h];
            #pragma unroll
            for (int r = 0; r < 4; ++r) {
                int l = wr * 64 + mi * 16 + g * 4 + r;
                if (l < L_) {
                    int tsv = tsIn[b * T_ + l];
                    float v = acc[mi][ni][r] + bp + posTab[(size_t)tsv * H_ + h];
                    outX[((size_t)b * L_ + l) * H_ + h] = v;
                }
            }
        }
    }
}

// ---------------- mask & ts side outputs (written as float values) -------
__global__ __launch_bounds__(256) void mask_ts(const int* __restrict__ mIn,
                                               const int* __restrict__ tIn,
                                               float* __restrict__ out) {
    int i = blockIdx.x * 256 + threadIdx.x;
    if (i >= B_ * L_) return;
    int b = i / L_, l = i % L_;
    const int* mb = mIn + b * T_ + 2 * l;
    int m = mb[0] * mb[1] * mb[2] * mb[3];
    const size_t offM = (size_t)B_ * L_ * H_;
    out[offM + i] = (float)m;
    out[offM + (size_t)B_ * L_ + i] = (float)tIn[b * T_ + l];
}

extern "C" void kernel_launch(void* const* d_in, const int* in_sizes, int n_in,
                              void* d_out, int out_size, void* d_ws, size_t ws_size,
                              hipStream_t stream) {
    (void)in_sizes; (void)n_in; (void)out_size; (void)ws_size;
    const float* spikes  = (const float*)d_in[0];
    const int*   smask   = (const int*)d_in[1];
    const int*   sts     = (const int*)d_in[2];
    const int*   dateIdx = (const int*)d_in[3];
    const float* Wemb    = (const float*)d_in[4];
    const float* bEmb    = (const float*)d_in[5];
    const float* Wproj   = (const float*)d_in[6];
    const float* bProj   = (const float*)d_in[7];
    const float* posTab  = (const float*)d_in[8];
    float* out = (float*)d_out;

    // workspace layout (bytes):
    // X1 bf16   [B][T][D]  : 50331648
    // SpB bf16  [B][T][C]  : 12582912
    // WeB bf16  [ND][D][C] : 18874368
    // WpB bf16  [H][KP]    : 12582912
    char* ws = (char*)d_ws;
    __hip_bfloat16* X1  = (__hip_bfloat16*)(ws);
    __hip_bfloat16* SpB = (__hip_bfloat16*)(ws + 50331648);
    __hip_bfloat16* WeB = (__hip_bfloat16*)(ws + 50331648 + 12582912);
    __hip_bfloat16* WpB = (__hip_bfloat16*)(ws + 50331648 + 12582912 + 18874368);

    static int smem_set = 0;
    if (!smem_set) {
        hipFuncSetAttribute((const void*)gemm1_embed,
                            hipFuncAttributeMaxDynamicSharedMemorySize, 3 * BUFB);
        hipFuncSetAttribute((const void*)gemm2_proj,
                            hipFuncAttributeMaxDynamicSharedMemorySize, 3 * BUFB);
        smem_set = 1;
    }

    cvt_bf16<<<6144, 256, 0, stream>>>(spikes, SpB, 1572864);   // 32*512*384
    cvt_bf16<<<9216, 256, 0, stream>>>(Wemb,  WeB, 2359296);    // 16*1536*384
    cvt_bf16<<<6144, 256, 0, stream>>>(Wproj, WpB, 1572864);    // 1024*6144

    dim3 g1(2, 12, 32);
    gemm1_embed<<<g1, 512, 3 * BUFB, stream>>>(SpB, WeB, bEmb, dateIdx, X1);

    dim3 g2(1, 8, 32);
    gemm2_proj<<<g2, 512, 3 * BUFB, stream>>>(X1, WpB, bProj, posTab, sts, out);

    mask_ts<<<32, 256, 0, stream>>>(smask, sts, out);
}

// Round 4
// 188.161 us; speedup vs baseline: 1.1685x; 1.0884x over previous
//
#include <hip/hip_runtime.h>
#include <hip/hip_bf16.h>

// Problem constants
#define B_    32
#define T_    512
#define C_    384
#define D_    1536      // C*MULT
#define H_    1024
#define L_    255       // (T-SIZE)/STRIDE + 1
#define KP_   6144      // SIZE*D
#define ND_   16

// GEMM template geometry: BM=256, BN=128, BK=64, 512 threads = 8 waves (4Mx2N),
// per-wave 64x64 output. Triple-buffered LDS (3 x 48KB = 144KB dynamic),
// counted vmcnt(12) pipeline: tile kt's loads issued at iter kt-2.
#define BUFB 49152      // bytes per LDS buffer (A 32KB + B 16KB)

using f32x4 = __attribute__((ext_vector_type(4))) float;
using s16x8 = __attribute__((ext_vector_type(8))) short;

__device__ __forceinline__ void gld_lds16(const void* g, void* l) {
    __builtin_amdgcn_global_load_lds(
        (const __attribute__((address_space(1))) void*)g,
        (__attribute__((address_space(3))) void*)l,
        16, 0, 0);
}

// ------------- prep: all f32->bf16 conversions + mask/ts, one launch ----
// 4-elem chunks: sp [0,1572864), we [.,+2359296), wp [.,+1572864),
// then 8160 mask/ts elements.
__global__ __launch_bounds__(256) void prep(
    const float* __restrict__ sp, const float* __restrict__ we,
    const float* __restrict__ wp, const int* __restrict__ mIn,
    const int* __restrict__ tIn,
    __hip_bfloat16* __restrict__ spB, __hip_bfloat16* __restrict__ weB,
    __hip_bfloat16* __restrict__ wpB, float* __restrict__ out) {
    int id = blockIdx.x * 256 + threadIdx.x;
    const float* src; __hip_bfloat16* dst; int idx;
    if (id < 1572864)       { src = sp; dst = spB; idx = id; }
    else if (id < 3932160)  { src = we; dst = weB; idx = id - 1572864; }
    else if (id < 5505024)  { src = wp; dst = wpB; idx = id - 3932160; }
    else {
        int i = id - 5505024;
        if (i < B_ * L_) {
            int b = i / L_, l = i % L_;
            const int* mb = mIn + b * T_ + 2 * l;
            int m = mb[0] * mb[1] * mb[2] * mb[3];
            const size_t offM = (size_t)B_ * L_ * H_;
            out[offM + i] = (float)m;
            out[offM + (size_t)B_ * L_ + i] = (float)tIn[b * T_ + l];
        }
        return;
    }
    float4 v = reinterpret_cast<const float4*>(src)[idx];
    __hip_bfloat16 o[4] = {__float2bfloat16(v.x), __float2bfloat16(v.y),
                           __float2bfloat16(v.z), __float2bfloat16(v.w)};
    reinterpret_cast<ushort4*>(dst)[idx] = *reinterpret_cast<ushort4*>(o);
}

// Compute one K-tile (BK=64, two ks-phases of 32) for this wave's 64x64 tile.
__device__ __forceinline__ void tile_compute(const char* la, const char* lb,
                                             f32x4 (&acc)[4][4],
                                             int rA, int rB, int g) {
    const int sxA = rA & 7, sxB = rB & 7;
    s16x8 af0[4], bf0[4], af1[4], bf1[4];
    #pragma unroll
    for (int mi = 0; mi < 4; ++mi)
        af0[mi] = *(const s16x8*)(la + rA * 128 + mi * 2048 + ((g ^ sxA) << 4));
    #pragma unroll
    for (int ni = 0; ni < 4; ++ni)
        bf0[ni] = *(const s16x8*)(lb + rB * 128 + ni * 2048 + ((g ^ sxB) << 4));
    #pragma unroll
    for (int mi = 0; mi < 4; ++mi)
        af1[mi] = *(const s16x8*)(la + rA * 128 + mi * 2048 + (((4 + g) ^ sxA) << 4));
    #pragma unroll
    for (int ni = 0; ni < 4; ++ni)
        bf1[ni] = *(const s16x8*)(lb + rB * 128 + ni * 2048 + (((4 + g) ^ sxB) << 4));
    asm volatile("s_waitcnt lgkmcnt(8)" ::: "memory");
    __builtin_amdgcn_sched_barrier(0);
    __builtin_amdgcn_s_setprio(1);
    #pragma unroll
    for (int mi = 0; mi < 4; ++mi)
        #pragma unroll
        for (int ni = 0; ni < 4; ++ni)
            acc[mi][ni] = __builtin_amdgcn_mfma_f32_16x16x32_bf16(
                af0[mi], bf0[ni], acc[mi][ni], 0, 0, 0);
    __builtin_amdgcn_s_setprio(0);
    asm volatile("s_waitcnt lgkmcnt(0)" ::: "memory");
    __builtin_amdgcn_sched_barrier(0);
    __builtin_amdgcn_s_setprio(1);
    #pragma unroll
    for (int mi = 0; mi < 4; ++mi)
        #pragma unroll
        for (int ni = 0; ni < 4; ++ni)
            acc[mi][ni] = __builtin_amdgcn_mfma_f32_16x16x32_bf16(
                af1[mi], bf1[ni], acc[mi][ni], 0, 0, 0);
    __builtin_amdgcn_s_setprio(0);
}

// ---------------- GEMM1: x1 = gelu(spikes @ Wg^T + bg) * 32, bf16 out ----
// 1-D grid 768; XCD batch-major: xcd=id&7 owns batches 4*xcd..4*xcd+3.
__global__ __launch_bounds__(512, 2) void gemm1_embed(
    const __hip_bfloat16* __restrict__ Sp,
    const __hip_bfloat16* __restrict__ We,
    const float* __restrict__ bEmb,
    const int* __restrict__ dateIdx,
    __hip_bfloat16* __restrict__ X1) {
    extern __shared__ __align__(16) char lds[];
    const int tid  = threadIdx.x;
    const int lane = tid & 63, wid = tid >> 6;
    const int wr = wid >> 1, wc = wid & 1;
    const int id   = blockIdx.x;            // 0..767
    const int xcd  = id & 7, slot = id >> 3; // slot 0..95
    const int b    = xcd * 4 + slot / 24;
    const int tile = slot % 24;
    const int m0   = (tile % 2) * 256;
    const int n0   = (tile / 2) * 128;
    const int didx = dateIdx[b];
    const __hip_bfloat16* A  = Sp + (size_t)b * T_ * C_;
    const __hip_bfloat16* Bm = We + (size_t)didx * D_ * C_;
    const int KT = C_ / 64;              // 6

    auto stage = [&](int kt, int buf) {
        char* lA = lds + buf * BUFB;
        char* lB = lA + 32768;
        int k0 = kt * 64;
        #pragma unroll
        for (int i = 0; i < 4; ++i) {
            int p = i * 512 + tid;
            int row = p >> 3;
            int clog = (p & 7) ^ (row & 7);
            gld_lds16(A + (size_t)(m0 + row) * C_ + k0 + clog * 8,
                      lA + (i * 512 + wid * 64) * 16);
        }
        #pragma unroll
        for (int i = 0; i < 2; ++i) {
            int p = i * 512 + tid;
            int row = p >> 3;
            int clog = (p & 7) ^ (row & 7);
            gld_lds16(Bm + (size_t)(n0 + row) * C_ + k0 + clog * 8,
                      lB + (i * 512 + wid * 64) * 16);
        }
    };

    f32x4 acc[4][4] = {};
    const int rl = lane & 15, g = lane >> 4;
    const int rA = wr * 64 + rl, rB = wc * 64 + rl;

    stage(0, 0);
    stage(1, 1);
    for (int kt = 0; kt < KT - 2; ++kt) {
        stage(kt + 2, (kt + 2) % 3);
        asm volatile("s_waitcnt vmcnt(12)" ::: "memory");
        __builtin_amdgcn_s_barrier();
        const char* la = lds + (kt % 3) * BUFB;
        tile_compute(la, la + 32768, acc, rA, rB, g);
        __builtin_amdgcn_s_barrier();
    }
    asm volatile("s_waitcnt vmcnt(6)" ::: "memory");
    __builtin_amdgcn_s_barrier();
    {
        const char* la = lds + ((KT - 2) % 3) * BUFB;
        tile_compute(la, la + 32768, acc, rA, rB, g);
    }
    asm volatile("s_waitcnt vmcnt(0)" ::: "memory");
    __builtin_amdgcn_s_barrier();
    {
        const char* la = lds + ((KT - 1) % 3) * BUFB;
        tile_compute(la, la + 32768, acc, rA, rB, g);
    }

    // epilogue: + bias, exact gelu, * 32, store bf16
    #pragma unroll
    for (int mi = 0; mi < 4; ++mi) {
        #pragma unroll
        for (int ni = 0; ni < 4; ++ni) {
            int col = n0 + wc * 64 + ni * 16 + rl;              // d
            float bg = bEmb[didx * D_ + col];
            #pragma unroll
            for (int r = 0; r < 4; ++r) {
                int row = m0 + wr * 64 + mi * 16 + g * 4 + r;   // t
                float v = acc[mi][ni][r] + bg;
                float gl = 0.5f * v * (1.0f + erff(v * 0.70710678118f)) * 32.0f;
                X1[((size_t)b * T_ + row) * D_ + col] = __float2bfloat16(gl);
            }
        }
    }
}

// ---------------- GEMM2: out = patches @ W_proj^T + b_proj + pos_table[ts]
// 1-D grid 256; XCD batch-major: xcd owns batches 4*xcd..4*xcd+3, 8 n-tiles
// of one batch co-resident on one XCD (A shared via its L2).
// K-tile order: kt -> (s = kt&3, dgroup = kt>>2) so the (s,s+2) duplicate
// A-rows are re-read 2 tiles later (L2-hot), not 48.
__global__ __launch_bounds__(512, 2) void gemm2_proj(
    const __hip_bfloat16* __restrict__ X1,
    const __hip_bfloat16* __restrict__ Wp,     // [H][KP] bf16
    const float* __restrict__ bProj,
    const float* __restrict__ posTab,          // [MAXF][H]
    const int* __restrict__ tsIn,              // [B][T]
    float* __restrict__ outX) {                // [B][L][H]
    extern __shared__ __align__(16) char lds[];
    const int tid  = threadIdx.x;
    const int lane = tid & 63, wid = tid >> 6;
    const int wr = wid >> 1, wc = wid & 1;
    const int id   = blockIdx.x;             // 0..255
    const int xcd  = id & 7, slot = id >> 3; // slot 0..31
    const int b    = xcd * 4 + (slot >> 3);
    const int n0   = (slot & 7) * 128;
    const __hip_bfloat16* Xb = X1 + (size_t)b * T_ * D_;
    const int KT = KP_ / 64;                   // 96

    auto stage = [&](int kt, int buf) {
        char* lA = lds + buf * BUFB;
        char* lB = lA + 32768;
        int s  = kt & 3;
        int d0 = (kt >> 2) * 64;
        int k0 = s * D_ + d0;                  // Wp column base
        #pragma unroll
        for (int i = 0; i < 4; ++i) {
            int p = i * 512 + tid;
            int row = p >> 3;
            int clog = (p & 7) ^ (row & 7);
            int l = row < 255 ? row : 254;
            gld_lds16(Xb + (size_t)(2 * l + s) * D_ + d0 + clog * 8,
                      lA + (i * 512 + wid * 64) * 16);
        }
        #pragma unroll
        for (int i = 0; i < 2; ++i) {
            int p = i * 512 + tid;
            int row = p >> 3;
            int clog = (p & 7) ^ (row & 7);
            gld_lds16(Wp + (size_t)(n0 + row) * KP_ + k0 + clog * 8,
                      lB + (i * 512 + wid * 64) * 16);
        }
    };

    f32x4 acc[4][4] = {};
    const int rl = lane & 15, g = lane >> 4;
    const int rA = wr * 64 + rl, rB = wc * 64 + rl;

    stage(0, 0);
    stage(1, 1);
    for (int kt = 0; kt < KT - 2; ++kt) {
        stage(kt + 2, (kt + 2) % 3);
        asm volatile("s_waitcnt vmcnt(12)" ::: "memory");
        __builtin_amdgcn_s_barrier();
        const char* la = lds + (kt % 3) * BUFB;
        tile_compute(la, la + 32768, acc, rA, rB, g);
        __builtin_amdgcn_s_barrier();
    }
    asm volatile("s_waitcnt vmcnt(6)" ::: "memory");
    __builtin_amdgcn_s_barrier();
    {
        const char* la = lds + ((KT - 2) % 3) * BUFB;
        tile_compute(la, la + 32768, acc, rA, rB, g);
    }
    asm volatile("s_waitcnt vmcnt(0)" ::: "memory");
    __builtin_amdgcn_s_barrier();
    {
        const char* la = lds + ((KT - 1) % 3) * BUFB;
        tile_compute(la, la + 32768, acc, rA, rB, g);
    }

    #pragma unroll
    for (int mi = 0; mi < 4; ++mi) {
        #pragma unroll
        for (int ni = 0; ni < 4; ++ni) {
            int h = n0 + wc * 64 + ni * 16 + rl;
            float bp = bProj[h];
            #pragma unroll
            for (int r = 0; r < 4; ++r) {
                int l = wr * 64 + mi * 16 + g * 4 + r;
                if (l < L_) {
                    int tsv = tsIn[b * T_ + l];
                    float v = acc[mi][ni][r] + bp + posTab[(size_t)tsv * H_ + h];
                    outX[((size_t)b * L_ + l) * H_ + h] = v;
                }
            }
        }
    }
}

extern "C" void kernel_launch(void* const* d_in, const int* in_sizes, int n_in,
                              void* d_out, int out_size, void* d_ws, size_t ws_size,
                              hipStream_t stream) {
    (void)in_sizes; (void)n_in; (void)out_size; (void)ws_size;
    const float* spikes  = (const float*)d_in[0];
    const int*   smask   = (const int*)d_in[1];
    const int*   sts     = (const int*)d_in[2];
    const int*   dateIdx = (const int*)d_in[3];
    const float* Wemb    = (const float*)d_in[4];
    const float* bEmb    = (const float*)d_in[5];
    const float* Wproj   = (const float*)d_in[6];
    const float* bProj   = (const float*)d_in[7];
    const float* posTab  = (const float*)d_in[8];
    float* out = (float*)d_out;

    // workspace layout (bytes):
    // X1 bf16   [B][T][D]  : 50331648
    // SpB bf16  [B][T][C]  : 12582912
    // WeB bf16  [ND][D][C] : 18874368
    // WpB bf16  [H][KP]    : 12582912
    char* ws = (char*)d_ws;
    __hip_bfloat16* X1  = (__hip_bfloat16*)(ws);
    __hip_bfloat16* SpB = (__hip_bfloat16*)(ws + 50331648);
    __hip_bfloat16* WeB = (__hip_bfloat16*)(ws + 50331648 + 12582912);
    __hip_bfloat16* WpB = (__hip_bfloat16*)(ws + 50331648 + 12582912 + 18874368);

    static int smem_set = 0;
    if (!smem_set) {
        hipFuncSetAttribute((const void*)gemm1_embed,
                            hipFuncAttributeMaxDynamicSharedMemorySize, 3 * BUFB);
        hipFuncSetAttribute((const void*)gemm2_proj,
                            hipFuncAttributeMaxDynamicSharedMemorySize, 3 * BUFB);
        smem_set = 1;
    }

    prep<<<21536, 256, 0, stream>>>(spikes, Wemb, Wproj, smask, sts,
                                    SpB, WeB, WpB, out);

    gemm1_embed<<<768, 512, 3 * BUFB, stream>>>(SpB, WeB, bEmb, dateIdx, X1);

    gemm2_proj<<<256, 512, 3 * BUFB, stream>>>(X1, WpB, bProj, posTab, sts, out);
}